// Round 1
// baseline (451.382 us; speedup 1.0000x reference)
//
#include <hip/hip_runtime.h>

// Sinkhorn-Knopp on B independent 8x8 fp32 matrices.
// One thread = one matrix, held entirely in VGPRs (64 floats, all indices
// compile-time constants after unrolling -> scalar-replaced into registers).
// Memory-bound: 256 MiB in + 256 MiB out; target ~6.3 TB/s.

#define N 8

__global__ __launch_bounds__(256) void sinkhorn8_kernel(
    const float* __restrict__ x,
    float* __restrict__ out,
    const int* __restrict__ num_iters_p,
    int B)
{
    int b = blockIdx.x * blockDim.x + threadIdx.x;
    if (b >= B) return;

    const int num_iters = *num_iters_p;

    const float4* __restrict__ xv = (const float4*)(x + (size_t)b * (N * N));
    float4* __restrict__ ov = (float4*)(out + (size_t)b * (N * N));

    float M[N * N];

    // Load + exp
#pragma unroll
    for (int k = 0; k < 16; ++k) {
        float4 v = xv[k];
        M[4 * k + 0] = __expf(v.x);
        M[4 * k + 1] = __expf(v.y);
        M[4 * k + 2] = __expf(v.z);
        M[4 * k + 3] = __expf(v.w);
    }

    for (int it = 0; it < num_iters; ++it) {
        // Row normalize
#pragma unroll
        for (int r = 0; r < N; ++r) {
            float s = 0.f;
#pragma unroll
            for (int c = 0; c < N; ++c) s += M[r * N + c];
            float inv = __builtin_amdgcn_rcpf(s);
#pragma unroll
            for (int c = 0; c < N; ++c) M[r * N + c] *= inv;
        }
        // Col normalize
#pragma unroll
        for (int c = 0; c < N; ++c) {
            float s = 0.f;
#pragma unroll
            for (int r = 0; r < N; ++r) s += M[r * N + c];
            float inv = __builtin_amdgcn_rcpf(s);
#pragma unroll
            for (int r = 0; r < N; ++r) M[r * N + c] *= inv;
        }
    }

    // Store
#pragma unroll
    for (int k = 0; k < 16; ++k) {
        float4 v;
        v.x = M[4 * k + 0];
        v.y = M[4 * k + 1];
        v.z = M[4 * k + 2];
        v.w = M[4 * k + 3];
        ov[k] = v;
    }
}

extern "C" void kernel_launch(void* const* d_in, const int* in_sizes, int n_in,
                              void* d_out, int out_size, void* d_ws, size_t ws_size,
                              hipStream_t stream) {
    const float* x = (const float*)d_in[0];
    const int* num_iters = (const int*)d_in[1];
    float* out = (float*)d_out;

    int B = in_sizes[0] / (N * N);  // 1048576 matrices
    int block = 256;
    int grid = (B + block - 1) / block;

    sinkhorn8_kernel<<<grid, block, 0, stream>>>(x, out, num_iters, B);
}